// Round 1
// baseline (979.600 us; speedup 1.0000x reference)
//
#include <hip/hip_runtime.h>
#include <hip/hip_bf16.h>
#include <math.h>

#define N_NODES   100000
#define N_EDGES   1600000
#define FDIM      128
#define NUM_GRAPHS 512
#define EPS       1e-5f

#define SCAN_BLOCKS ((N_NODES + 1023) / 1024)   // 98

// ---------------- degree / CSR build ----------------

__global__ void k_count(const int* __restrict__ dst, int* __restrict__ counts) {
    int e = blockIdx.x * blockDim.x + threadIdx.x;
    if (e < N_EDGES) atomicAdd(&counts[dst[e]], 1);
}

__global__ void k_dinv(const int* __restrict__ counts, float* __restrict__ dinv) {
    int i = blockIdx.x * blockDim.x + threadIdx.x;
    if (i < N_NODES) dinv[i] = rsqrtf(1.0f + (float)counts[i]);
}

__global__ void k_scan1(const int* __restrict__ counts, int* __restrict__ excl,
                        int* __restrict__ bsum) {
    __shared__ int lds[256];
    int t = threadIdx.x;
    int base = blockIdx.x * 1024 + t * 4;
    int v0 = 0, v1 = 0, v2 = 0, v3 = 0;
    if (base + 0 < N_NODES) v0 = counts[base + 0];
    if (base + 1 < N_NODES) v1 = counts[base + 1];
    if (base + 2 < N_NODES) v2 = counts[base + 2];
    if (base + 3 < N_NODES) v3 = counts[base + 3];
    int s = v0 + v1 + v2 + v3;
    lds[t] = s;
    __syncthreads();
    for (int off = 1; off < 256; off <<= 1) {
        int y = 0;
        if (t >= off) y = lds[t - off];
        __syncthreads();
        if (t >= off) lds[t] += y;
        __syncthreads();
    }
    int start = lds[t] - s;   // exclusive prefix within block
    if (base + 0 < N_NODES) excl[base + 0] = start;
    if (base + 1 < N_NODES) excl[base + 1] = start + v0;
    if (base + 2 < N_NODES) excl[base + 2] = start + v0 + v1;
    if (base + 3 < N_NODES) excl[base + 3] = start + v0 + v1 + v2;
    if (t == 255) bsum[blockIdx.x] = lds[255];
}

__global__ void k_scan2(int* __restrict__ bsum, int nb) {
    __shared__ int lds[256];
    int t = threadIdx.x;
    int v = (t < nb) ? bsum[t] : 0;
    lds[t] = v;
    __syncthreads();
    for (int off = 1; off < 256; off <<= 1) {
        int y = 0;
        if (t >= off) y = lds[t - off];
        __syncthreads();
        if (t >= off) lds[t] += y;
        __syncthreads();
    }
    if (t < nb) bsum[t] = lds[t] - v;   // exclusive
}

__global__ void k_scan3(int* __restrict__ excl, const int* __restrict__ bsum) {
    int t = threadIdx.x;
    int base = blockIdx.x * 1024 + t * 4;
    int add = bsum[blockIdx.x];
#pragma unroll
    for (int j = 0; j < 4; j++)
        if (base + j < N_NODES) excl[base + j] += add;
    if (blockIdx.x == 0 && t == 0) excl[N_NODES] = N_EDGES;
}

__global__ void k_scatter(const int* __restrict__ src, const int* __restrict__ dst,
                          const float* __restrict__ dinv,
                          const int* __restrict__ offs, int* __restrict__ cursor,
                          int* __restrict__ csr_src, float* __restrict__ csr_w) {
    int e = blockIdx.x * blockDim.x + threadIdx.x;
    if (e >= N_EDGES) return;
    int d = dst[e], s = src[e];
    int pos = offs[d] + atomicAdd(&cursor[d], 1);
    csr_src[pos] = s;
    csr_w[pos]   = dinv[s] * dinv[d];
}

// ---------------- GEMM: C[N,128] = A[N,128] @ W[128,128] ----------------

#define GR 64   // rows per block

__global__ __launch_bounds__(256) void k_gemm(const float* __restrict__ A,
                                              const float* __restrict__ W,
                                              float* __restrict__ C) {
    __shared__ float wl[128 * 128];          // 64 KB
    __shared__ float xl[GR * 132];           // padded rows (33 float4)
    int t = threadIdx.x;

    // stage W (16384 floats, 64 float4/thread-group)
    const float4* W4 = (const float4*)W;
    float4* wl4 = (float4*)wl;
#pragma unroll
    for (int i = 0; i < 16; i++) wl4[t + i * 256] = W4[t + i * 256];

    // stage x tile (64 rows x 128), float4, padded stride 132 floats
    int r0 = blockIdx.x * GR;
#pragma unroll
    for (int i = 0; i < 8; i++) {
        int q  = t + i * 256;       // float4 index within tile
        int r  = q >> 5;            // 32 float4 per row
        int k4 = q & 31;
        int row = r0 + r;
        float4 v = make_float4(0.f, 0.f, 0.f, 0.f);
        if (row < N_NODES) v = ((const float4*)A)[(size_t)row * 32 + k4];
        *(float4*)&xl[r * 132 + k4 * 4] = v;
    }
    __syncthreads();

    int rg = t >> 4, cg = t & 15;   // 16 rowgroups x 16 colgroups
    float acc[4][8];
#pragma unroll
    for (int i = 0; i < 4; i++)
#pragma unroll
        for (int j = 0; j < 8; j++) acc[i][j] = 0.f;

#pragma unroll 4
    for (int k = 0; k < 128; k++) {
        float a0 = xl[(rg * 4 + 0) * 132 + k];
        float a1 = xl[(rg * 4 + 1) * 132 + k];
        float a2 = xl[(rg * 4 + 2) * 132 + k];
        float a3 = xl[(rg * 4 + 3) * 132 + k];
        float4 w0 = *(const float4*)&wl[k * 128 + cg * 8];
        float4 w1 = *(const float4*)&wl[k * 128 + cg * 8 + 4];
        float wv[8] = {w0.x, w0.y, w0.z, w0.w, w1.x, w1.y, w1.z, w1.w};
#pragma unroll
        for (int j = 0; j < 8; j++) {
            acc[0][j] = fmaf(a0, wv[j], acc[0][j]);
            acc[1][j] = fmaf(a1, wv[j], acc[1][j]);
            acc[2][j] = fmaf(a2, wv[j], acc[2][j]);
            acc[3][j] = fmaf(a3, wv[j], acc[3][j]);
        }
    }

#pragma unroll
    for (int i = 0; i < 4; i++) {
        int row = r0 + rg * 4 + i;
        if (row < N_NODES) {
            float4 o0 = make_float4(acc[i][0], acc[i][1], acc[i][2], acc[i][3]);
            float4 o1 = make_float4(acc[i][4], acc[i][5], acc[i][6], acc[i][7]);
            float4* cp = (float4*)(C + (size_t)row * 128 + cg * 8);
            cp[0] = o0;
            cp[1] = o1;
        }
    }
}

// ---------------- fused aggregate + bias + LayerNorm + ReLU ----------------
// one wave per node, 2 features per lane

__global__ __launch_bounds__(256) void k_agg(const float* __restrict__ h,
                                             float* __restrict__ out,
                                             const int* __restrict__ offs,
                                             const int* __restrict__ csr_src,
                                             const float* __restrict__ csr_w,
                                             const float* __restrict__ dinv,
                                             const float* __restrict__ bias,
                                             const float* __restrict__ gamma,
                                             const float* __restrict__ beta) {
    int wave = threadIdx.x >> 6;
    int lane = threadIdx.x & 63;
    int i = blockIdx.x * 4 + wave;
    if (i >= N_NODES) return;

    float di = dinv[i];
    float self = di * di;
    float2 hv = ((const float2*)(h + (size_t)i * 128))[lane];
    float ax = hv.x * self, ay = hv.y * self;

    int e0 = offs[i], e1 = offs[i + 1];
    for (int e = e0; e < e1; ++e) {
        int s = csr_src[e];
        float w = csr_w[e];
        float2 v = ((const float2*)(h + (size_t)s * 128))[lane];
        ax = fmaf(v.x, w, ax);
        ay = fmaf(v.y, w, ay);
    }
    ax += bias[lane * 2];
    ay += bias[lane * 2 + 1];

    float s1 = ax + ay;
    float s2 = ax * ax + ay * ay;
#pragma unroll
    for (int off = 32; off; off >>= 1) {
        s1 += __shfl_xor(s1, off);
        s2 += __shfl_xor(s2, off);
    }
    float mu  = s1 * (1.0f / 128.0f);
    float var = s2 * (1.0f / 128.0f) - mu * mu;
    float rstd = rsqrtf(var + EPS);

    float ox = (ax - mu) * rstd * gamma[lane * 2]     + beta[lane * 2];
    float oy = (ay - mu) * rstd * gamma[lane * 2 + 1] + beta[lane * 2 + 1];
    ox = fmaxf(ox, 0.f);
    oy = fmaxf(oy, 0.f);
    ((float2*)(out + (size_t)i * 128))[lane] = make_float2(ox, oy);
}

// ---------------- pool (mean per graph) + final linear ----------------
// batch is sorted; one wave per graph, binary-search segment bounds

__global__ __launch_bounds__(64) void k_pool(const float* __restrict__ h,
                                             const int* __restrict__ batch,
                                             const float* __restrict__ Wl,
                                             const float* __restrict__ bl,
                                             float* __restrict__ out) {
    int g = blockIdx.x;
    int lane = threadIdx.x;

    int lo = 0, hi = N_NODES;
    while (lo < hi) { int mid = (lo + hi) >> 1; if (batch[mid] < g) lo = mid + 1; else hi = mid; }
    int s = lo;
    lo = s; hi = N_NODES;
    while (lo < hi) { int mid = (lo + hi) >> 1; if (batch[mid] < g + 1) lo = mid + 1; else hi = mid; }
    int e = lo;

    float accx = 0.f, accy = 0.f;
    for (int n = s; n < e; ++n) {
        float2 v = ((const float2*)(h + (size_t)n * 128))[lane];
        accx += v.x;
        accy += v.y;
    }
    float cnt = fmaxf((float)(e - s), 1.0f);
    float inv = 1.0f / cnt;
    float p = accx * inv * Wl[lane * 2] + accy * inv * Wl[lane * 2 + 1];
#pragma unroll
    for (int off = 32; off; off >>= 1) p += __shfl_xor(p, off);
    if (lane == 0) out[g] = p + bl[0];
}

// ---------------- launch ----------------

extern "C" void kernel_launch(void* const* d_in, const int* in_sizes, int n_in,
                              void* d_out, int out_size, void* d_ws, size_t ws_size,
                              hipStream_t stream) {
    const float* x     = (const float*)d_in[0];
    const int*   ei    = (const int*)d_in[1];
    const int*   batch = (const int*)d_in[2];
    const float* W1 = (const float*)d_in[3];
    const float* b1 = (const float*)d_in[4];
    const float* g1 = (const float*)d_in[5];
    const float* be1 = (const float*)d_in[6];
    const float* W2 = (const float*)d_in[7];
    const float* b2 = (const float*)d_in[8];
    const float* g2 = (const float*)d_in[9];
    const float* be2 = (const float*)d_in[10];
    const float* W3 = (const float*)d_in[11];
    const float* b3 = (const float*)d_in[12];
    const float* g3 = (const float*)d_in[13];
    const float* be3 = (const float*)d_in[14];
    const float* Wl = (const float*)d_in[15];
    const float* bl = (const float*)d_in[16];

    const int* src = ei;
    const int* dst = ei + N_EDGES;

    char* ws = (char*)d_ws;
    size_t off = 0;
    auto alloc = [&](size_t bytes) -> void* {
        void* p = ws + off;
        off += (bytes + 255) & ~(size_t)255;
        return p;
    };
    float* hA      = (float*)alloc((size_t)N_NODES * FDIM * 4);
    float* hB      = (float*)alloc((size_t)N_NODES * FDIM * 4);
    float* dinv    = (float*)alloc((size_t)N_NODES * 4);
    int*   counts  = (int*)alloc((size_t)N_NODES * 4);
    int*   offs    = (int*)alloc((size_t)(N_NODES + 1) * 4);
    int*   cursor  = (int*)alloc((size_t)N_NODES * 4);
    int*   csr_src = (int*)alloc((size_t)N_EDGES * 4);
    float* csr_w   = (float*)alloc((size_t)N_EDGES * 4);
    int*   bsum    = (int*)alloc(256 * 4);

    hipMemsetAsync(counts, 0, (size_t)N_NODES * 4, stream);
    hipMemsetAsync(cursor, 0, (size_t)N_NODES * 4, stream);

    k_count<<<(N_EDGES + 255) / 256, 256, 0, stream>>>(dst, counts);
    k_dinv<<<(N_NODES + 255) / 256, 256, 0, stream>>>(counts, dinv);
    k_scan1<<<SCAN_BLOCKS, 256, 0, stream>>>(counts, offs, bsum);
    k_scan2<<<1, 256, 0, stream>>>(bsum, SCAN_BLOCKS);
    k_scan3<<<SCAN_BLOCKS, 256, 0, stream>>>(offs, bsum);
    k_scatter<<<(N_EDGES + 255) / 256, 256, 0, stream>>>(src, dst, dinv, offs, cursor,
                                                         csr_src, csr_w);

    int gemm_grid = (N_NODES + GR - 1) / GR;
    int agg_grid  = (N_NODES + 3) / 4;

    // layer 1
    k_gemm<<<gemm_grid, 256, 0, stream>>>(x, W1, hB);
    k_agg<<<agg_grid, 256, 0, stream>>>(hB, hA, offs, csr_src, csr_w, dinv, b1, g1, be1);
    // layer 2
    k_gemm<<<gemm_grid, 256, 0, stream>>>(hA, W2, hB);
    k_agg<<<agg_grid, 256, 0, stream>>>(hB, hA, offs, csr_src, csr_w, dinv, b2, g2, be2);
    // layer 3
    k_gemm<<<gemm_grid, 256, 0, stream>>>(hA, W3, hB);
    k_agg<<<agg_grid, 256, 0, stream>>>(hB, hA, offs, csr_src, csr_w, dinv, b3, g3, be3);

    // pool + linear
    k_pool<<<NUM_GRAPHS, 64, 0, stream>>>(hA, batch, Wl, bl, (float*)d_out);
}

// Round 2
// 477.583 us; speedup vs baseline: 2.0512x; 2.0512x over previous
//
#include <hip/hip_runtime.h>
#include <hip/hip_bf16.h>
#include <math.h>

#define N_NODES    100000
#define N_EDGES    1600000
#define FDIM       128
#define NUM_GRAPHS 512
#define EPS        1e-5f
#define PADN       100096           // 782 * 128

#define SCAN_BLOCKS ((N_NODES + 1023) / 1024)   // 98

typedef __attribute__((ext_vector_type(8))) __bf16 bf16x8;
typedef __attribute__((ext_vector_type(4))) float  f32x4;

__device__ __forceinline__ unsigned short f2bf(float f) {
    unsigned u = __builtin_bit_cast(unsigned, f);
    u += 0x7FFF + ((u >> 16) & 1);           // round-to-nearest-even
    return (unsigned short)(u >> 16);
}
__device__ __forceinline__ float bf2f(unsigned short b) {
    unsigned u = ((unsigned)b) << 16;
    return __builtin_bit_cast(float, u);
}

// ---------------- degree / CSR build ----------------

__global__ void k_count(const int* __restrict__ dst, int* __restrict__ counts) {
    int e = blockIdx.x * blockDim.x + threadIdx.x;
    if (e < N_EDGES) atomicAdd(&counts[dst[e]], 1);
}

__global__ void k_dinv(const int* __restrict__ counts, float* __restrict__ dinv) {
    int i = blockIdx.x * blockDim.x + threadIdx.x;
    if (i < N_NODES) dinv[i] = rsqrtf(1.0f + (float)counts[i]);
}

__global__ void k_scan1(const int* __restrict__ counts, int* __restrict__ excl,
                        int* __restrict__ bsum) {
    __shared__ int lds[256];
    int t = threadIdx.x;
    int base = blockIdx.x * 1024 + t * 4;
    int v0 = 0, v1 = 0, v2 = 0, v3 = 0;
    if (base + 0 < N_NODES) v0 = counts[base + 0];
    if (base + 1 < N_NODES) v1 = counts[base + 1];
    if (base + 2 < N_NODES) v2 = counts[base + 2];
    if (base + 3 < N_NODES) v3 = counts[base + 3];
    int s = v0 + v1 + v2 + v3;
    lds[t] = s;
    __syncthreads();
    for (int off = 1; off < 256; off <<= 1) {
        int y = 0;
        if (t >= off) y = lds[t - off];
        __syncthreads();
        if (t >= off) lds[t] += y;
        __syncthreads();
    }
    int start = lds[t] - s;
    if (base + 0 < N_NODES) excl[base + 0] = start;
    if (base + 1 < N_NODES) excl[base + 1] = start + v0;
    if (base + 2 < N_NODES) excl[base + 2] = start + v0 + v1;
    if (base + 3 < N_NODES) excl[base + 3] = start + v0 + v1 + v2;
    if (t == 255) bsum[blockIdx.x] = lds[255];
}

__global__ void k_scan2(int* __restrict__ bsum, int nb) {
    __shared__ int lds[256];
    int t = threadIdx.x;
    int v = (t < nb) ? bsum[t] : 0;
    lds[t] = v;
    __syncthreads();
    for (int off = 1; off < 256; off <<= 1) {
        int y = 0;
        if (t >= off) y = lds[t - off];
        __syncthreads();
        if (t >= off) lds[t] += y;
        __syncthreads();
    }
    if (t < nb) bsum[t] = lds[t] - v;
}

__global__ void k_scan3(int* __restrict__ excl, const int* __restrict__ bsum) {
    int t = threadIdx.x;
    int base = blockIdx.x * 1024 + t * 4;
    int add = bsum[blockIdx.x];
#pragma unroll
    for (int j = 0; j < 4; j++)
        if (base + j < N_NODES) excl[base + j] += add;
    if (blockIdx.x == 0 && t == 0) excl[N_NODES] = N_EDGES;
}

__global__ void k_scatter(const int* __restrict__ src, const int* __restrict__ dst,
                          const float* __restrict__ dinv,
                          const int* __restrict__ offs, int* __restrict__ cursor,
                          int* __restrict__ csr_src, float* __restrict__ csr_w) {
    int e = blockIdx.x * blockDim.x + threadIdx.x;
    if (e >= N_EDGES) return;
    int d = dst[e], s = src[e];
    int pos = offs[d] + atomicAdd(&cursor[d], 1);
    csr_src[pos] = s;
    csr_w[pos]   = dinv[s] * dinv[d];
}

// ---------------- f32 -> bf16 conversion of x (padded) ----------------

__global__ __launch_bounds__(256) void k_cvt_x(const float* __restrict__ x,
                                               unsigned short* __restrict__ xb) {
    long long idx = ((long long)blockIdx.x * 256 + threadIdx.x) * 4;
    if (idx >= (long long)PADN * FDIM) return;
    ushort4 o;
    if (idx < (long long)N_NODES * FDIM) {
        float4 v = *(const float4*)(x + idx);
        o.x = f2bf(v.x); o.y = f2bf(v.y); o.z = f2bf(v.z); o.w = f2bf(v.w);
    } else {
        o.x = o.y = o.z = o.w = 0;
    }
    *(ushort4*)(xb + idx) = o;
}

// ---------------- W pack: f32 [128][128] -> bf16 MFMA A-operand frags -------
// out[((ks*8 + ct)*64 + lane)*8 + j] = W[ks*32 + (lane>>4)*8 + j][ct*16 + (lane&15)]

__global__ __launch_bounds__(256) void k_wpack(const float* __restrict__ W1,
                                               const float* __restrict__ W2,
                                               const float* __restrict__ W3,
                                               unsigned short* __restrict__ wp) {
    const float* W = (blockIdx.y == 0) ? W1 : (blockIdx.y == 1) ? W2 : W3;
    unsigned short* o = wp + (size_t)blockIdx.y * 16384;
    int idx = blockIdx.x * 256 + threadIdx.x;          // 0..16383
    int j  = idx & 7;
    int l  = (idx >> 3) & 63;
    int ct = (idx >> 9) & 7;
    int ks = idx >> 12;
    int k  = ks * 32 + (l >> 4) * 8 + j;
    int c  = ct * 16 + (l & 15);
    o[idx] = f2bf(W[k * 128 + c]);
}

// ---------------- GEMM: C[N,128] = A[N,128] @ W  (bf16 MFMA, computes C^T) --
// block = 256 thr = 4 waves; block covers 128 node rows; no LDS, no barriers.

__global__ __launch_bounds__(256) void k_gemm(const unsigned short* __restrict__ A,
                                              const unsigned short* __restrict__ Wp,
                                              unsigned short* __restrict__ C) {
    int t    = threadIdx.x;
    int lane = t & 63;
    int w    = t >> 6;
    int wc   = w & 1;           // 4 col-tiles each
    int wr   = w >> 1;          // 4 row-tiles each
    int rb   = blockIdx.x * 128 + wr * 64 + (lane & 15);
    int koff = (lane >> 4) * 8;

    f32x4 acc[4][4];
#pragma unroll
    for (int c = 0; c < 4; c++)
#pragma unroll
        for (int r = 0; r < 4; r++) acc[c][r] = (f32x4){0.f, 0.f, 0.f, 0.f};

    const bf16x8* Wv = (const bf16x8*)Wp;
#pragma unroll
    for (int ks = 0; ks < 4; ++ks) {
        bf16x8 fw[4], fa[4];
#pragma unroll
        for (int c = 0; c < 4; ++c)
            fw[c] = Wv[(ks * 8 + wc * 4 + c) * 64 + lane];
#pragma unroll
        for (int r = 0; r < 4; ++r) {
            const uint4 v = *(const uint4*)(A + (size_t)(rb + r * 16) * 128 + ks * 32 + koff);
            fa[r] = __builtin_bit_cast(bf16x8, v);
        }
#pragma unroll
        for (int c = 0; c < 4; ++c)
#pragma unroll
            for (int r = 0; r < 4; ++r)
                acc[c][r] = __builtin_amdgcn_mfma_f32_16x16x32_bf16(fw[c], fa[r], acc[c][r], 0, 0, 0);
    }

    // D[dr][dc]: dr = feature col = (wc*4+c)*16 + (lane>>4)*4 + j ; dc = node row
#pragma unroll
    for (int r = 0; r < 4; ++r) {
        int row = blockIdx.x * 128 + wr * 64 + r * 16 + (lane & 15);
        if (row < N_NODES) {
#pragma unroll
            for (int c = 0; c < 4; ++c) {
                int col = (wc * 4 + c) * 16 + (lane >> 4) * 4;
                ushort4 o;
                o.x = f2bf(acc[c][r][0]);
                o.y = f2bf(acc[c][r][1]);
                o.z = f2bf(acc[c][r][2]);
                o.w = f2bf(acc[c][r][3]);
                *(ushort4*)(C + (size_t)row * 128 + col) = o;
            }
        }
    }
}

// ---------------- fused aggregate + bias + LayerNorm + ReLU (bf16) ----------
// 16 lanes per node (ushort8 = 16B/lane), 4 nodes per wave, 16 nodes per block

__global__ __launch_bounds__(256) void k_agg(const unsigned short* __restrict__ h,
                                             unsigned short* __restrict__ out,
                                             const int* __restrict__ offs,
                                             const int* __restrict__ csr_src,
                                             const float* __restrict__ csr_w,
                                             const float* __restrict__ dinv,
                                             const float* __restrict__ bias,
                                             const float* __restrict__ gamma,
                                             const float* __restrict__ beta) {
    int t    = threadIdx.x;
    int lane = t & 63;
    int sub  = lane >> 4;        // group within wave
    int sl   = lane & 15;        // lane within group
    int i    = blockIdx.x * 16 + (t >> 6) * 4 + sub;   // 6250*16 == 100000 exact

    float di = dinv[i];
    float selfw = di * di;

    float a0, a1, a2, a3, a4, a5, a6, a7;
    {
        uint4 v = *(const uint4*)(h + (size_t)i * 128 + sl * 8);
        a0 = bf2f((unsigned short)(v.x & 0xffff)) * selfw;
        a1 = bf2f((unsigned short)(v.x >> 16))    * selfw;
        a2 = bf2f((unsigned short)(v.y & 0xffff)) * selfw;
        a3 = bf2f((unsigned short)(v.y >> 16))    * selfw;
        a4 = bf2f((unsigned short)(v.z & 0xffff)) * selfw;
        a5 = bf2f((unsigned short)(v.z >> 16))    * selfw;
        a6 = bf2f((unsigned short)(v.w & 0xffff)) * selfw;
        a7 = bf2f((unsigned short)(v.w >> 16))    * selfw;
    }

    int e0 = offs[i], e1 = offs[i + 1];
    for (int e = e0; e < e1; ++e) {
        int   s   = csr_src[e];
        float wgt = csr_w[e];
        uint4 v = *(const uint4*)(h + (size_t)s * 128 + sl * 8);
        a0 = fmaf(bf2f((unsigned short)(v.x & 0xffff)), wgt, a0);
        a1 = fmaf(bf2f((unsigned short)(v.x >> 16)),    wgt, a1);
        a2 = fmaf(bf2f((unsigned short)(v.y & 0xffff)), wgt, a2);
        a3 = fmaf(bf2f((unsigned short)(v.y >> 16)),    wgt, a3);
        a4 = fmaf(bf2f((unsigned short)(v.z & 0xffff)), wgt, a4);
        a5 = fmaf(bf2f((unsigned short)(v.z >> 16)),    wgt, a5);
        a6 = fmaf(bf2f((unsigned short)(v.w & 0xffff)), wgt, a6);
        a7 = fmaf(bf2f((unsigned short)(v.w >> 16)),    wgt, a7);
    }

    float4 b0 = *(const float4*)(bias + sl * 8);
    float4 b1 = *(const float4*)(bias + sl * 8 + 4);
    a0 += b0.x; a1 += b0.y; a2 += b0.z; a3 += b0.w;
    a4 += b1.x; a5 += b1.y; a6 += b1.z; a7 += b1.w;

    float s1 = a0 + a1 + a2 + a3 + a4 + a5 + a6 + a7;
    float s2 = a0*a0 + a1*a1 + a2*a2 + a3*a3 + a4*a4 + a5*a5 + a6*a6 + a7*a7;
#pragma unroll
    for (int off = 1; off < 16; off <<= 1) {
        s1 += __shfl_xor(s1, off);
        s2 += __shfl_xor(s2, off);
    }
    float mu   = s1 * (1.0f / 128.0f);
    float var  = s2 * (1.0f / 128.0f) - mu * mu;
    float rstd = rsqrtf(var + EPS);

    float4 g0 = *(const float4*)(gamma + sl * 8);
    float4 g1 = *(const float4*)(gamma + sl * 8 + 4);
    float4 e0v = *(const float4*)(beta + sl * 8);
    float4 e1v = *(const float4*)(beta + sl * 8 + 4);

    float r0 = fmaxf((a0 - mu) * rstd * g0.x + e0v.x, 0.f);
    float r1 = fmaxf((a1 - mu) * rstd * g0.y + e0v.y, 0.f);
    float r2 = fmaxf((a2 - mu) * rstd * g0.z + e0v.z, 0.f);
    float r3 = fmaxf((a3 - mu) * rstd * g0.w + e0v.w, 0.f);
    float r4 = fmaxf((a4 - mu) * rstd * g1.x + e1v.x, 0.f);
    float r5 = fmaxf((a5 - mu) * rstd * g1.y + e1v.y, 0.f);
    float r6 = fmaxf((a6 - mu) * rstd * g1.z + e1v.z, 0.f);
    float r7 = fmaxf((a7 - mu) * rstd * g1.w + e1v.w, 0.f);

    uint4 o;
    o.x = (unsigned)f2bf(r0) | ((unsigned)f2bf(r1) << 16);
    o.y = (unsigned)f2bf(r2) | ((unsigned)f2bf(r3) << 16);
    o.z = (unsigned)f2bf(r4) | ((unsigned)f2bf(r5) << 16);
    o.w = (unsigned)f2bf(r6) | ((unsigned)f2bf(r7) << 16);
    *(uint4*)(out + (size_t)i * 128 + sl * 8) = o;
}

// ---------------- pool (mean per graph) + final linear ----------------

__global__ __launch_bounds__(256) void k_pool(const unsigned short* __restrict__ h,
                                              const int* __restrict__ batch,
                                              const float* __restrict__ Wl,
                                              const float* __restrict__ bl,
                                              float* __restrict__ out) {
    __shared__ float2 part[4][64];
    int g = blockIdx.x;
    int t = threadIdx.x, w = t >> 6, lane = t & 63;

    int lo = 0, hi = N_NODES;
    while (lo < hi) { int mid = (lo + hi) >> 1; if (batch[mid] < g) lo = mid + 1; else hi = mid; }
    int s = lo;
    lo = s; hi = N_NODES;
    while (lo < hi) { int mid = (lo + hi) >> 1; if (batch[mid] < g + 1) lo = mid + 1; else hi = mid; }
    int e = lo;

    float ax = 0.f, ay = 0.f;
    for (int n = s + w; n < e; n += 4) {
        unsigned v = *(const unsigned*)(h + (size_t)n * 128 + lane * 2);
        ax += bf2f((unsigned short)(v & 0xffff));
        ay += bf2f((unsigned short)(v >> 16));
    }
    part[w][lane] = make_float2(ax, ay);
    __syncthreads();
    if (t < 64) {
        float sx = part[0][lane].x + part[1][lane].x + part[2][lane].x + part[3][lane].x;
        float sy = part[0][lane].y + part[1][lane].y + part[2][lane].y + part[3][lane].y;
        float cnt = fmaxf((float)(e - s), 1.0f);
        float inv = 1.0f / cnt;
        float p = sx * inv * Wl[lane * 2] + sy * inv * Wl[lane * 2 + 1];
#pragma unroll
        for (int off = 32; off; off >>= 1) p += __shfl_xor(p, off);
        if (lane == 0) out[g] = p + bl[0];
    }
}

// ---------------- launch ----------------

extern "C" void kernel_launch(void* const* d_in, const int* in_sizes, int n_in,
                              void* d_out, int out_size, void* d_ws, size_t ws_size,
                              hipStream_t stream) {
    const float* x     = (const float*)d_in[0];
    const int*   ei    = (const int*)d_in[1];
    const int*   batch = (const int*)d_in[2];
    const float* W1 = (const float*)d_in[3];
    const float* b1 = (const float*)d_in[4];
    const float* g1 = (const float*)d_in[5];
    const float* be1 = (const float*)d_in[6];
    const float* W2 = (const float*)d_in[7];
    const float* b2 = (const float*)d_in[8];
    const float* g2 = (const float*)d_in[9];
    const float* be2 = (const float*)d_in[10];
    const float* W3 = (const float*)d_in[11];
    const float* b3 = (const float*)d_in[12];
    const float* g3 = (const float*)d_in[13];
    const float* be3 = (const float*)d_in[14];
    const float* Wl = (const float*)d_in[15];
    const float* bl = (const float*)d_in[16];

    const int* src = ei;
    const int* dst = ei + N_EDGES;

    char* ws = (char*)d_ws;
    size_t off = 0;
    auto alloc = [&](size_t bytes) -> void* {
        void* p = ws + off;
        off += (bytes + 255) & ~(size_t)255;
        return p;
    };
    unsigned short* xb   = (unsigned short*)alloc((size_t)PADN * FDIM * 2);
    unsigned short* hA   = (unsigned short*)alloc((size_t)PADN * FDIM * 2);
    unsigned short* hB   = (unsigned short*)alloc((size_t)PADN * FDIM * 2);
    unsigned short* wp   = (unsigned short*)alloc((size_t)3 * 16384 * 2);
    float* dinv    = (float*)alloc((size_t)N_NODES * 4);
    int*   counts  = (int*)alloc((size_t)N_NODES * 4);
    int*   offs    = (int*)alloc((size_t)(N_NODES + 1) * 4);
    int*   cursor  = (int*)alloc((size_t)N_NODES * 4);
    int*   csr_src = (int*)alloc((size_t)N_EDGES * 4);
    float* csr_w   = (float*)alloc((size_t)N_EDGES * 4);
    int*   bsum    = (int*)alloc(256 * 4);

    hipMemsetAsync(counts, 0, (size_t)N_NODES * 4, stream);
    hipMemsetAsync(cursor, 0, (size_t)N_NODES * 4, stream);

    // CSR build + conversions
    k_count<<<(N_EDGES + 255) / 256, 256, 0, stream>>>(dst, counts);
    k_dinv<<<(N_NODES + 255) / 256, 256, 0, stream>>>(counts, dinv);
    k_scan1<<<SCAN_BLOCKS, 256, 0, stream>>>(counts, offs, bsum);
    k_scan2<<<1, 256, 0, stream>>>(bsum, SCAN_BLOCKS);
    k_scan3<<<SCAN_BLOCKS, 256, 0, stream>>>(offs, bsum);
    k_scatter<<<(N_EDGES + 255) / 256, 256, 0, stream>>>(src, dst, dinv, offs, cursor,
                                                         csr_src, csr_w);
    k_cvt_x<<<(PADN * FDIM / 4 + 255) / 256, 256, 0, stream>>>(x, xb);
    k_wpack<<<dim3(64, 3), 256, 0, stream>>>(W1, W2, W3, wp);

    int gemm_grid = PADN / 128;          // 782
    int agg_grid  = N_NODES / 16;        // 6250

    // layer 1
    k_gemm<<<gemm_grid, 256, 0, stream>>>(xb, wp, hB);
    k_agg<<<agg_grid, 256, 0, stream>>>(hB, hA, offs, csr_src, csr_w, dinv, b1, g1, be1);
    // layer 2
    k_gemm<<<gemm_grid, 256, 0, stream>>>(hA, wp + 16384, hB);
    k_agg<<<agg_grid, 256, 0, stream>>>(hB, hA, offs, csr_src, csr_w, dinv, b2, g2, be2);
    // layer 3
    k_gemm<<<gemm_grid, 256, 0, stream>>>(hA, wp + 32768, hB);
    k_agg<<<agg_grid, 256, 0, stream>>>(hB, hA, offs, csr_src, csr_w, dinv, b3, g3, be3);

    // pool + linear
    k_pool<<<NUM_GRAPHS, 256, 0, stream>>>(hA, batch, Wl, bl, (float*)d_out);
}